// Round 10
// baseline (211.676 us; speedup 1.0000x reference)
//
#include <hip/hip_runtime.h>
#include <hip/hip_bf16.h>

typedef __hip_bfloat16 bf16;
typedef __hip_bfloat162 bf16x2;
typedef __attribute__((ext_vector_type(8))) short short8;
typedef __attribute__((ext_vector_type(4))) float f32x4;

__device__ __forceinline__ void storeOut(float* p, float v) { *p = v; }
__device__ __forceinline__ void storeOut(bf16* p, float v) { *p = __float2bfloat16(v); }

#define GLOAD_LDS16(g, l)                                              \
  __builtin_amdgcn_global_load_lds(                                    \
      (const __attribute__((address_space(1))) void*)(g),              \
      (__attribute__((address_space(3))) void*)(l), 16, 0, 0)

// ---------------- prep: fp32->bf16 convert of x + both weight transposes ----------------
__global__ __launch_bounds__(256) void prep_kernel(const float* __restrict__ x,
                                                   const float* __restrict__ w_qkv,
                                                   const float* __restrict__ w_proj,
                                                   bf16* __restrict__ xb,
                                                   bf16* __restrict__ wqkvT,
                                                   bf16* __restrict__ wprojT)
{
  int bid = blockIdx.x;
  if (bid < 9408) {                       // cvt: 50176*384 elems, 2048/block
    int i = bid * 256 + threadIdx.x;
    const float4* p = (const float4*)x + (size_t)i * 2;
    float4 a = p[0], b = p[1];
    union { short8 v; bf16 h[8]; } u;
    u.h[0] = __float2bfloat16(a.x); u.h[1] = __float2bfloat16(a.y);
    u.h[2] = __float2bfloat16(a.z); u.h[3] = __float2bfloat16(a.w);
    u.h[4] = __float2bfloat16(b.x); u.h[5] = __float2bfloat16(b.y);
    u.h[6] = __float2bfloat16(b.z); u.h[7] = __float2bfloat16(b.w);
    *((short8*)xb + i) = u.v;
  } else {                                // transposes: 1152*384 + 384*384 elems
    int idx = (bid - 9408) * 256 + threadIdx.x;
    if (idx < 1152 * 384) {
      int n = idx / 384, k = idx - n * 384;
      wqkvT[idx] = __float2bfloat16(w_qkv[(size_t)k * 1152 + n]);
    } else {
      idx -= 1152 * 384;
      int n = idx / 384, k = idx - n * 384;
      wprojT[idx] = __float2bfloat16(w_proj[(size_t)k * 384 + n]);
    }
  }
}

// ---------------- MFMA GEMM: 256x128 tile, 8 waves, BK=32, DOUBLE-buffered ----------------
// T3 minimum 2-phase: prologue STAGE+sync; body {STAGE(next) -> ds_read+MFMA(cur) -> sync}.
// LDS = 2 x (16KB A + 8KB B) = 48 KB -> 3 blocks/CU (same as round-9 single-buffer).
// Bank swizzle: BK=32 rows are 64B (4 x 16B slots); slot q' = q ^ ((row>>1)&3)
// (round-3 config, measured 0 conflicts). XCD swizzle: m204 bijective.
template<typename TC, bool BIAS>
__global__ __launch_bounds__(512) void gemm_mfma(const bf16* __restrict__ A,
                                                 const bf16* __restrict__ Bt,
                                                 const float* __restrict__ bias,
                                                 TC* __restrict__ C,
                                                 int M, int N, int K, int nbx)
{
  __shared__ __align__(16) bf16 As[2][256 * 32];   // 2 x 16 KB
  __shared__ __align__(16) bf16 Bs[2][128 * 32];   // 2 x 8 KB
  const int tid = threadIdx.x;
  const int wave = tid >> 6, lane = tid & 63;
  // bijective XCD swizzle (m204)
  const int nwg = gridDim.x;
  const int qc = nwg >> 3, rr = nwg & 7;
  const int xcd = blockIdx.x & 7, jj = blockIdx.x >> 3;
  const int wg = (xcd < rr ? xcd * (qc + 1) : rr * (qc + 1) + (xcd - rr) * qc) + jj;
  const int by = wg / nbx, bx = wg - by * nbx;
  const int bm = by * 256, bn = bx * 128;
  const int wr = wave >> 1, wc = wave & 1;      // 4 x 2 wave grid

  f32x4 acc[4][4] = {};

  // staging: flat byte F = e*8192 + tid*16 -> row F>>6, slot (F>>4)&3.
  // global source slot XOR-swizzled with ((row>>1)&3); reads deswizzle the same.
  const bf16* aP[2];
  const bf16* bP0;
#pragma unroll
  for (int e = 0; e < 2; ++e) {
    int flat = e * 8192 + tid * 16;
    int r = flat >> 6;
    int q = ((flat >> 4) & 3) ^ ((r >> 1) & 3);
    aP[e] = A + (size_t)(bm + r) * K + q * 8;
  }
  {
    int flat = tid * 16;
    int r = flat >> 6;
    int q = ((flat >> 4) & 3) ^ ((r >> 1) & 3);
    bP0 = Bt + (size_t)(bn + r) * K + q * 8;
  }

  auto STAGE = [&](int buf, int k0) {
    char* aw = (char*)(&As[buf][0]) + wave * 1024;   // wave-uniform dest, linear
    char* bw = (char*)(&Bs[buf][0]) + wave * 1024;
    GLOAD_LDS16(aP[0] + k0, aw);
    GLOAD_LDS16(aP[1] + k0, aw + 8192);
    GLOAD_LDS16(bP0 + k0, bw);
  };

  const int lr = lane & 15, lk = lane >> 4;
  const int rbA = (wr * 64 + lr) * 32;
  const int rbB = (wc * 64 + lr) * 32;
  const int qx = (lk ^ ((lr >> 1) & 3)) * 8;    // deswizzled slot (row%64 = lr)

  const int nt = K >> 5;                        // 12 steps for K=384
  STAGE(0, 0);
  __syncthreads();
  int cur = 0;
  for (int t = 0; t < nt; ++t) {
    if (t + 1 < nt) STAGE(cur ^ 1, (t + 1) << 5);   // fly during compute
    const bf16* Ab = &As[cur][0];
    const bf16* Bb = &Bs[cur][0];
    short8 af[4], bfr[4];
#pragma unroll
    for (int i = 0; i < 4; ++i) af[i]  = *(const short8*)(Ab + rbA + i * 512 + qx);
#pragma unroll
    for (int j = 0; j < 4; ++j) bfr[j] = *(const short8*)(Bb + rbB + j * 512 + qx);
#pragma unroll
    for (int i = 0; i < 4; ++i)
#pragma unroll
      for (int j = 0; j < 4; ++j)
        acc[i][j] = __builtin_amdgcn_mfma_f32_16x16x32_bf16(af[i], bfr[j], acc[i][j], 0, 0, 0);
    __syncthreads();                      // drains next-tile stage; all reads of cur done
    cur ^= 1;
  }

  const int crow = bm + wr * 64 + lk * 4;
  const int ccol = bn + wc * 64 + lr;
#pragma unroll
  for (int j = 0; j < 4; ++j) {
    int col = ccol + j * 16;
    float bv = BIAS ? bias[col] : 0.f;
#pragma unroll
    for (int i = 0; i < 4; ++i)
#pragma unroll
      for (int t = 0; t < 4; ++t) {
        int row = crow + i * 16 + t;
        storeOut(&C[(size_t)row * N + col], acc[i][j][t] + bv);
      }
  }
}

// ---------------- Pooling (both scales): mean + max ----------------
__global__ __launch_bounds__(128) void pool_both_kernel(const bf16* __restrict__ temp,
                                                        bf16* __restrict__ pool1,
                                                        bf16* __restrict__ pool2)
{
  int blk = blockIdx.x;
  bf16* outp; int oh, k, isc;
  if (blk < 3 * 16 * 28 * 28) { outp = pool1; oh = 28; k = 2; isc = 1; }
  else { blk -= 3 * 16 * 28 * 28; outp = pool2; oh = 14; k = 4; isc = 2; }
  const int ow = oh;
  int c = threadIdx.x;
  int x = blk % ow; int t = blk / ow;
  int y = t % oh;  t /= oh;
  int b = t % 16;  int s = t / 16;
  float sum = 0.f, mx = -3.4e38f;
  float inv = 1.0f / (float)(k * k);
  for (int dy = 0; dy < k; ++dy)
    for (int dx = 0; dx < k; ++dx) {
      int h = y * k + dy, w = x * k + dx;
      float v = __bfloat162float(temp[((size_t)b * 3136 + h * 56 + w) * 1152 + s * 384 + isc * 128 + c]);
      sum += v; mx = fmaxf(mx, v);
    }
  outp[((size_t)(s * 16 + b) * oh * ow + y * ow + x) * 128 + c] = __float2bfloat16(sum * inv + mx);
}

// ---------------- MFMA window attention, all 3 scales in one launch ----------------
struct AttnP {
  const bf16 *qb, *kb, *vb;
  bf16* out;
  int R, Rw, ow, npos, rstride, out_cstride, out_coffset, blk0;
  long long bstride;
};

__global__ __launch_bounds__(256) void attn_mfma(const float* __restrict__ btable,
                                                 AttnP P0, AttnP P1, AttnP P2)
{
  __shared__ __align__(16) bf16 KP[4 * 4096];      // [h]: K rows [64][40] then P [64][64]
  __shared__ __align__(16) bf16 Vt[4 * 2048];      // [h][d][pp] swizzled, pp>=49 zeroed
  __shared__ float bias_s[169];

  const AttnP p = (blockIdx.x >= (unsigned)P2.blk0) ? P2
                : (blockIdx.x >= (unsigned)P1.blk0) ? P1 : P0;
  const int blk = blockIdx.x - p.blk0;
  const int b = blk / p.R, r = blk % p.R;
  const int rh = r / p.Rw, rw = r % p.Rw;
  const int tid = threadIdx.x;
  const int h = tid >> 6, lane = tid & 63;
  const int lr = lane & 15, lk = lane >> 4;
  const int hb = r & 3;

  if (tid < 169) bias_s[tid] = btable[tid * 4 + hb];

  const size_t gbase = (size_t)b * p.bstride;

  // K staging: 784 16B chunks (4 heads x 49 rows x 4 slots)
  for (int c = tid; c < 784; c += 256) {
    int hh = c / 196, rem = c - hh * 196;
    int row = rem >> 2, slot = rem & 3;
    int r7 = (row * 9363) >> 16, rm = row - r7 * 7;
    int n = (rh * 7 + r7) * p.ow + rw * 7 + rm;
    short8 v = *(const short8*)(p.kb + gbase + (size_t)n * p.rstride + hh * 32 + slot * 8);
    *(short8*)(KP + hh * 4096 + row * 40 + slot * 8) = v;
  }
  // V staging, transposed + swizzled + zero-padded
  for (int j = tid; j < 4096; j += 256) {
    int pp = j & 63, dp = (j >> 6) & 15, hh = j >> 10;
    bf16 v0, v1;
    if (pp < 49) {
      int r7 = (pp * 9363) >> 16, rm = pp - r7 * 7;
      int n = (rh * 7 + r7) * p.ow + rw * 7 + rm;
      bf16x2 v2 = *(const bf16x2*)(p.vb + gbase + (size_t)n * p.rstride + hh * 32 + dp * 2);
      v0 = v2.x; v1 = v2.y;
    } else { v0 = __float2bfloat16(0.f); v1 = v0; }
    int d0 = dp * 2, d1 = d0 + 1;
    Vt[hh * 2048 + d0 * 64 + ((pp >> 3) ^ (d0 & 7)) * 8 + (pp & 7)] = v0;
    Vt[hh * 2048 + d1 * 64 + ((pp >> 3) ^ (d1 & 7)) * 8 + (pp & 7)] = v1;
  }

  // Q fragments straight from global (A-layout: row=lane&15, k=lk*8..+8)
  short8 qa[4];
#pragma unroll
  for (int it = 0; it < 4; ++it) {
    int pq = it * 16 + lr; pq = min(pq, 48);
    int r7 = (pq * 9363) >> 16, rm = pq - r7 * 7;
    int n = (rh * 7 + r7) * p.ow + rw * 7 + rm;
    qa[it] = *(const short8*)(p.qb + gbase + (size_t)n * p.rstride + h * 32 + lk * 8);
  }

  __syncthreads();

  // QK^T: 16 MFMAs (K=32, single k-step)
  f32x4 s[4][4];
  {
    short8 kf[4];
#pragma unroll
    for (int jt = 0; jt < 4; ++jt)
      kf[jt] = *(const short8*)(KP + h * 4096 + (jt * 16 + lr) * 40 + lk * 8);
    const f32x4 z = {0.f, 0.f, 0.f, 0.f};
    __builtin_amdgcn_s_setprio(1);
#pragma unroll
    for (int it = 0; it < 4; ++it)
#pragma unroll
      for (int jt = 0; jt < 4; ++jt)
        s[it][jt] = __builtin_amdgcn_mfma_f32_16x16x32_bf16(qa[it], kf[jt], z, 0, 0, 0);
    __builtin_amdgcn_s_setprio(0);
  }

  // scale + bias + pad-mask + softmax (rows = lane&15 butterfly groups)
  const float scale = 0.17677669529663687f;
  const bool colpad = (lr != 0);               // jt==3: pp = 48+lr >= 49
  int pp7[4], ppm[4];
#pragma unroll
  for (int jt = 0; jt < 4; ++jt) {
    int pp = min(jt * 16 + lr, 48);
    pp7[jt] = (pp * 9363) >> 16; ppm[jt] = pp - pp7[jt] * 7;
  }
  float sm[4][4];
#pragma unroll
  for (int it = 0; it < 4; ++it)
#pragma unroll
    for (int t = 0; t < 4; ++t) {
      int pq = min(it * 16 + lk * 4 + t, 48);
      int q7 = (pq * 9363) >> 16, qm = pq - q7 * 7;
#pragma unroll
      for (int jt = 0; jt < 4; ++jt) {
        float bv = bias_s[(q7 - pp7[jt] + 6) * 13 + (qm - ppm[jt] + 6)];
        float v = fmaf(s[it][jt][t], scale, bv);
        if (jt == 3 && colpad) v = -1e30f;
        s[it][jt][t] = v;
      }
      float m = fmaxf(fmaxf(s[it][0][t], s[it][1][t]), fmaxf(s[it][2][t], s[it][3][t]));
      m = fmaxf(m, __shfl_xor(m, 1));
      m = fmaxf(m, __shfl_xor(m, 2));
      m = fmaxf(m, __shfl_xor(m, 4));
      m = fmaxf(m, __shfl_xor(m, 8));
      float ssum = 0.f;
#pragma unroll
      for (int jt = 0; jt < 4; ++jt) {
        float e = __expf(s[it][jt][t] - m);
        s[it][jt][t] = e; ssum += e;
      }
      ssum += __shfl_xor(ssum, 1);
      ssum += __shfl_xor(ssum, 2);
      ssum += __shfl_xor(ssum, 4);
      ssum += __shfl_xor(ssum, 8);
      sm[it][t] = 1.0f / ssum;
    }

  // P (unnormalized, <=1) -> same per-head LDS block (K is dead), XOR-swizzled
#pragma unroll
  for (int it = 0; it < 4; ++it)
#pragma unroll
    for (int t = 0; t < 4; ++t) {
      int prow = it * 16 + lk * 4 + t;
#pragma unroll
      for (int jt = 0; jt < 4; ++jt) {
        int slot = (jt * 2 + (lr >> 3)) ^ (prow & 7);
        KP[h * 4096 + prow * 64 + slot * 8 + (lr & 7)] = __float2bfloat16(s[it][jt][t]);
      }
    }
  __syncthreads();

  // PV: 16 MFMAs over 2 k-steps (pp 0..31, 32..63)
  f32x4 o[4][2] = {};
#pragma unroll
  for (int ks = 0; ks < 2; ++ks) {
    short8 pf[4], vf[2];
#pragma unroll
    for (int it = 0; it < 4; ++it) {
      int prow = it * 16 + lr;
      pf[it] = *(const short8*)(KP + h * 4096 + prow * 64 + ((ks * 4 + lk) ^ (prow & 7)) * 8);
    }
#pragma unroll
    for (int jd = 0; jd < 2; ++jd) {
      int d = jd * 16 + lr;
      vf[jd] = *(const short8*)(Vt + h * 2048 + d * 64 + ((ks * 4 + lk) ^ (d & 7)) * 8);
    }
    __builtin_amdgcn_s_setprio(1);
#pragma unroll
    for (int it = 0; it < 4; ++it)
#pragma unroll
      for (int jd = 0; jd < 2; ++jd)
        o[it][jd] = __builtin_amdgcn_mfma_f32_16x16x32_bf16(pf[it], vf[jd], o[it][jd], 0, 0, 0);
    __builtin_amdgcn_s_setprio(0);
  }

  // scrambled output scatter (matches reference reshape semantics)
  const int c0 = (r & 3) * 32;
#pragma unroll
  for (int it = 0; it < 4; ++it)
#pragma unroll
    for (int t = 0; t < 4; ++t) {
      int prow = it * 16 + lk * 4 + t;
      if (prow < 49) {
        int m_out = (h * (p.R >> 2) + (r >> 2)) * 49 + prow;
        bf16* op = p.out + ((size_t)b * p.npos + m_out) * p.out_cstride + p.out_coffset + c0;
#pragma unroll
        for (int jd = 0; jd < 2; ++jd)
          op[jd * 16 + lr] = __float2bfloat16(o[it][jd][t] * sm[it][t]);
      }
    }
}

// ---------------- Fused bilinear upsample for both scales ----------------
__device__ __forceinline__ float2 bilerp2(const bf16* __restrict__ base, int dim, int h, int w, int cp)
{
  float r = (float)dim / 56.f;
  float uy = (h + 0.5f) * r - 0.5f;
  float ux = (w + 0.5f) * r - 0.5f;
  float fy0 = floorf(uy), fx0 = floorf(ux);
  int y0 = (int)fy0, x0 = (int)fx0;
  float fy = uy - fy0, fx = ux - fx0;
  int y0c = max(y0, 0), y1c = min(y0 + 1, dim - 1);
  int x0c = max(x0, 0), x1c = min(x0 + 1, dim - 1);
  bf16x2 v00 = *(const bf16x2*)(base + ((size_t)y0c * dim + x0c) * 128 + cp * 2);
  bf16x2 v01 = *(const bf16x2*)(base + ((size_t)y0c * dim + x1c) * 128 + cp * 2);
  bf16x2 v10 = *(const bf16x2*)(base + ((size_t)y1c * dim + x0c) * 128 + cp * 2);
  bf16x2 v11 = *(const bf16x2*)(base + ((size_t)y1c * dim + x1c) * 128 + cp * 2);
  float w00 = (1.f - fy) * (1.f - fx), w01 = (1.f - fy) * fx;
  float w10 = fy * (1.f - fx),        w11 = fy * fx;
  float2 o;
  o.x = w00 * __bfloat162float(v00.x) + w01 * __bfloat162float(v01.x) +
        w10 * __bfloat162float(v10.x) + w11 * __bfloat162float(v11.x);
  o.y = w00 * __bfloat162float(v00.y) + w01 * __bfloat162float(v01.y) +
        w10 * __bfloat162float(v10.y) + w11 * __bfloat162float(v11.y);
  return o;
}

__global__ __launch_bounds__(256) void upsample_both_kernel(const bf16* __restrict__ yb1,
                                                            const bf16* __restrict__ yb2,
                                                            bf16* __restrict__ fused)
{
  int t = blockIdx.x * 256 + threadIdx.x;
  int cp = t & 63;
  int pos = t >> 6;
  int n = pos % 3136, b = pos / 3136;
  int h = n / 56, w = n % 56;
  float2 s1 = bilerp2(yb1 + (size_t)b * 784 * 128, 28, h, w, cp);
  float2 s2 = bilerp2(yb2 + (size_t)b * 196 * 128, 14, h, w, cp);
  bf16* op = fused + (size_t)pos * 384;
  bf16x2 o1; o1.x = __float2bfloat16(s1.x); o1.y = __float2bfloat16(s1.y);
  bf16x2 o2; o2.x = __float2bfloat16(s2.x); o2.y = __float2bfloat16(s2.y);
  *(bf16x2*)(op + 128 + cp * 2) = o1;
  *(bf16x2*)(op + 256 + cp * 2) = o2;
}

extern "C" void kernel_launch(void* const* d_in, const int* in_sizes, int n_in,
                              void* d_out, int out_size, void* d_ws, size_t ws_size,
                              hipStream_t stream)
{
  const float* x      = (const float*)d_in[0];
  const float* w_qkv  = (const float*)d_in[1];
  const float* w_proj = (const float*)d_in[2];
  const float* b_proj = (const float*)d_in[3];
  const float* btable = (const float*)d_in[4];

  bf16* temp  = (bf16*)d_ws;                          // 50176 x 1152
  bf16* pool1 = temp  + (size_t)50176 * 1152;         // 3 x 16 x 784 x 128
  bf16* pool2 = pool1 + (size_t)3 * 16 * 784 * 128;   // 3 x 16 x 196 x 128
  bf16* fused = pool2 + (size_t)3 * 16 * 196 * 128;   // 50176 x 384 (also xb)
  bf16* ybuf1 = fused + (size_t)50176 * 384;          // 16 x 784 x 128
  bf16* ybuf2 = ybuf1 + (size_t)16 * 784 * 128;       // 16 x 196 x 128
  bf16* wqkvT = ybuf2 + (size_t)16 * 196 * 128;       // 1152 x 384
  bf16* wprojT= wqkvT + (size_t)1152 * 384;           // 384 x 384
  bf16* xb    = fused;   // x in bf16, dead before attention writes fused

  // 0) prep: cvt + transposes in one launch
  prep_kernel<<<9408 + 2304, 256, 0, stream>>>(x, w_qkv, w_proj, xb, wqkvT, wprojT);

  // 1) QKV projection: temp = xb @ wqkvT^T  (196 x 9 = 1764 blocks, 512 thr)
  gemm_mfma<bf16, false><<<1764, 512, 0, stream>>>(
      xb, wqkvT, nullptr, temp, 50176, 1152, 384, 9);

  // 2) pooling for scales 1,2 (mean + max), one launch
  pool_both_kernel<<<3 * 16 * 28 * 28 + 3 * 16 * 14 * 14, 128, 0, stream>>>(temp, pool1, pool2);

  // 3) MFMA window attention, all scales in one launch
  AttnP P0{temp, temp + 384, temp + 768, fused,
           64, 8, 56, 3136, 1152, 384, 0, 0, (long long)3136 * 1152};
  AttnP P1{pool1, pool1 + (size_t)16 * 784 * 128, pool1 + (size_t)2 * 16 * 784 * 128, ybuf1,
           16, 4, 28, 784, 128, 128, 0, 1024, (long long)784 * 128};
  AttnP P2{pool2, pool2 + (size_t)16 * 196 * 128, pool2 + (size_t)2 * 16 * 196 * 128, ybuf2,
           4, 2, 14, 196, 128, 128, 0, 1280, (long long)196 * 128};
  attn_mfma<<<1344, 256, 0, stream>>>(btable, P0, P1, P2);

  // 4) fused bilinear upsample into fused channels [128,256) and [256,384)
  upsample_both_kernel<<<16 * 3136 * 64 / 256, 256, 0, stream>>>(ybuf1, ybuf2, fused);

  // 5) output projection: out = fused @ wprojT^T + b_proj (196 x 3 = 588 blocks)
  gemm_mfma<float, true><<<588, 512, 0, stream>>>(
      fused, wprojT, b_proj, (float*)d_out, 50176, 384, 384, 3);
}

// Round 11
// 204.941 us; speedup vs baseline: 1.0329x; 1.0329x over previous
//
#include <hip/hip_runtime.h>
#include <hip/hip_bf16.h>

typedef __hip_bfloat16 bf16;
typedef __hip_bfloat162 bf16x2;
typedef __attribute__((ext_vector_type(8))) short short8;
typedef __attribute__((ext_vector_type(4))) float f32x4;

__device__ __forceinline__ float bf2f(short v) {
  return __uint_as_float(((unsigned)(unsigned short)v) << 16);
}
__device__ __forceinline__ void storeOut(float* p, float v) { *p = v; }
__device__ __forceinline__ void storeOut(bf16* p, float v) { *p = __float2bfloat16(v); }

#define GLOAD_LDS16(g, l)                                              \
  __builtin_amdgcn_global_load_lds(                                    \
      (const __attribute__((address_space(1))) void*)(g),              \
      (__attribute__((address_space(3))) void*)(l), 16, 0, 0)

// ---------------- prep: fp32->bf16 convert of x + both weight transposes ----------------
__global__ __launch_bounds__(256) void prep_kernel(const float* __restrict__ x,
                                                   const float* __restrict__ w_qkv,
                                                   const float* __restrict__ w_proj,
                                                   bf16* __restrict__ xb,
                                                   bf16* __restrict__ wqkvT,
                                                   bf16* __restrict__ wprojT)
{
  int bid = blockIdx.x;
  if (bid < 9408) {                       // cvt: 50176*384 elems, 2048/block
    int i = bid * 256 + threadIdx.x;
    const float4* p = (const float4*)x + (size_t)i * 2;
    float4 a = p[0], b = p[1];
    union { short8 v; bf16 h[8]; } u;
    u.h[0] = __float2bfloat16(a.x); u.h[1] = __float2bfloat16(a.y);
    u.h[2] = __float2bfloat16(a.z); u.h[3] = __float2bfloat16(a.w);
    u.h[4] = __float2bfloat16(b.x); u.h[5] = __float2bfloat16(b.y);
    u.h[6] = __float2bfloat16(b.z); u.h[7] = __float2bfloat16(b.w);
    *((short8*)xb + i) = u.v;
  } else {                                // transposes: 1152*384 + 384*384 elems
    int idx = (bid - 9408) * 256 + threadIdx.x;
    if (idx < 1152 * 384) {
      int n = idx / 384, k = idx - n * 384;
      wqkvT[idx] = __float2bfloat16(w_qkv[(size_t)k * 1152 + n]);
    } else {
      idx -= 1152 * 384;
      int n = idx / 384, k = idx - n * 384;
      wprojT[idx] = __float2bfloat16(w_proj[(size_t)k * 384 + n]);
    }
  }
}

// ---------------- MFMA GEMM: 256x128 tile, 8 waves, BK=64, single-buffer ----------------
// Round-9 verified config (65 us GEMM1; 2-phase structural ceiling per guide m233).
template<typename TC, bool BIAS>
__global__ __launch_bounds__(512) void gemm_mfma(const bf16* __restrict__ A,
                                                 const bf16* __restrict__ Bt,
                                                 const float* __restrict__ bias,
                                                 TC* __restrict__ C,
                                                 int M, int N, int K, int nbx)
{
  __shared__ __align__(16) bf16 As[256 * 64];   // 32 KB
  __shared__ __align__(16) bf16 Bs[128 * 64];   // 16 KB
  const int tid = threadIdx.x;
  const int wave = tid >> 6, lane = tid & 63;
  // bijective XCD swizzle (m204)
  const int nwg = gridDim.x;
  const int qc = nwg >> 3, rr = nwg & 7;
  const int xcd = blockIdx.x & 7, jj = blockIdx.x >> 3;
  const int wg = (xcd < rr ? xcd * (qc + 1) : rr * (qc + 1) + (xcd - rr) * qc) + jj;
  const int by = wg / nbx, bx = wg - by * nbx;
  const int bm = by * 256, bn = bx * 128;
  const int wr = wave >> 1, wc = wave & 1;      // 4 x 2 wave grid

  f32x4 acc[4][4] = {};

  const bf16* aP[4];
  const bf16* bP[2];
#pragma unroll
  for (int e = 0; e < 4; ++e) {
    int flat = e * 8192 + tid * 16;
    int r = flat >> 7;
    int q = ((flat >> 4) & 7) ^ (r & 7);
    aP[e] = A + (size_t)(bm + r) * K + q * 8;
  }
#pragma unroll
  for (int e = 0; e < 2; ++e) {
    int flat = e * 8192 + tid * 16;
    int r = flat >> 7;
    int q = ((flat >> 4) & 7) ^ (r & 7);
    bP[e] = Bt + (size_t)(bn + r) * K + q * 8;
  }
  char* AsW = (char*)As + wave * 1024;   // wave-uniform dest, linear
  char* BsW = (char*)Bs + wave * 1024;

  const int lr = lane & 15, lk = lane >> 4;
  const int rbA = (wr * 64 + lr) * 64;
  const int rbB = (wc * 64 + lr) * 64;
  const int q0 = ((lk    ) ^ (lr & 7)) * 8;
  const int q1 = ((4 + lk) ^ (lr & 7)) * 8;

  for (int k0 = 0; k0 < K; k0 += 64) {
#pragma unroll
    for (int e = 0; e < 4; ++e) GLOAD_LDS16(aP[e] + k0, AsW + e * 8192);
#pragma unroll
    for (int e = 0; e < 2; ++e) GLOAD_LDS16(bP[e] + k0, BsW + e * 8192);
    __syncthreads();
    short8 af0[4], af1[4], bf0[4], bf1[4];
#pragma unroll
    for (int i = 0; i < 4; ++i) {
      af0[i] = *(const short8*)(As + rbA + i * 1024 + q0);
      af1[i] = *(const short8*)(As + rbA + i * 1024 + q1);
    }
#pragma unroll
    for (int j = 0; j < 4; ++j) {
      bf0[j] = *(const short8*)(Bs + rbB + j * 1024 + q0);
      bf1[j] = *(const short8*)(Bs + rbB + j * 1024 + q1);
    }
#pragma unroll
    for (int i = 0; i < 4; ++i)
#pragma unroll
      for (int j = 0; j < 4; ++j) {
        acc[i][j] = __builtin_amdgcn_mfma_f32_16x16x32_bf16(af0[i], bf0[j], acc[i][j], 0, 0, 0);
        acc[i][j] = __builtin_amdgcn_mfma_f32_16x16x32_bf16(af1[i], bf1[j], acc[i][j], 0, 0, 0);
      }
    __syncthreads();
  }

  const int crow = bm + wr * 64 + lk * 4;
  const int ccol = bn + wc * 64 + lr;
#pragma unroll
  for (int j = 0; j < 4; ++j) {
    int col = ccol + j * 16;
    float bv = BIAS ? bias[col] : 0.f;
#pragma unroll
    for (int i = 0; i < 4; ++i)
#pragma unroll
      for (int t = 0; t < 4; ++t) {
        int row = crow + i * 16 + t;
        storeOut(&C[(size_t)row * N + col], acc[i][j][t] + bv);
      }
  }
}

// ---------------- MFMA window attention + fused on-the-fly pooling ----------------
// Block = one window; 4 waves = 4 heads. P=49 padded to 64.
// Scales 1,2 (f=2,4) pool mean+max from temp during staging (same fp32 accumulation
// order as the old pool kernel -> bit-identical operands). Heavy f=4 blocks launch
// first (blk0 order P2,P1,P0) so their latency hides under the 1024 f=1 blocks.
struct AttnP {
  const bf16 *qb, *kb, *vb;
  bf16* out;
  int R, Rw, f, npos, out_cstride, out_coffset, blk0;
};

__global__ __launch_bounds__(256) void attn_mfma(const float* __restrict__ btable,
                                                 AttnP P0, AttnP P1, AttnP P2)
{
  __shared__ __align__(16) bf16 KP[4 * 4096];      // [h]: K rows [64][40] then P [64][64]
  __shared__ __align__(16) bf16 Vt[4 * 2048];      // [h][d][pp] swizzled, pp>=49 zeroed
  __shared__ float bias_s[169];

  const AttnP p = (blockIdx.x >= (unsigned)P0.blk0) ? P0
                : (blockIdx.x >= (unsigned)P1.blk0) ? P1 : P2;
  const int blk = blockIdx.x - p.blk0;
  const int b = blk / p.R, r = blk % p.R;
  const int rh = r / p.Rw, rw = r % p.Rw;
  const int tid = threadIdx.x;
  const int h = tid >> 6, lane = tid & 63;
  const int lr = lane & 15, lk = lane >> 4;
  const int hb = r & 3;
  const int f = p.f;
  const float pinv = 1.0f / (float)(f * f);

  if (tid < 169) bias_s[tid] = btable[tid * 4 + hb];

  const size_t gbase = (size_t)b * 3136 * 1152;

  // K staging: 784 chunk-jobs (4 heads x 49 rows x 4 slots of 8 ch), pooled if f>1
  for (int c = tid; c < 784; c += 256) {
    int hh = c / 196, rem = c - hh * 196;
    int row = rem >> 2, slot = rem & 3;
    int r7 = (row * 9363) >> 16, rm = row - r7 * 7;
    const bf16* src = p.kb + gbase +
        ((size_t)((rh * 7 + r7) * f) * 56 + (rw * 7 + rm) * f) * 1152 + hh * 32 + slot * 8;
    short8 ov;
    if (f == 1) {
      ov = *(const short8*)src;
    } else {
      float sum[8] = {}, mx[8];
#pragma unroll
      for (int e = 0; e < 8; ++e) mx[e] = -3.4e38f;
      for (int dy = 0; dy < f; ++dy)
        for (int dx = 0; dx < f; ++dx) {
          short8 v = *(const short8*)(src + ((size_t)dy * 56 + dx) * 1152);
#pragma unroll
          for (int e = 0; e < 8; ++e) {
            float fv = bf2f(v[e]); sum[e] += fv; mx[e] = fmaxf(mx[e], fv);
          }
        }
      union { short8 v; bf16 hh2[8]; } u;
#pragma unroll
      for (int e = 0; e < 8; ++e) u.hh2[e] = __float2bfloat16(sum[e] * pinv + mx[e]);
      ov = u.v;
    }
    *(short8*)(KP + hh * 4096 + row * 40 + slot * 8) = ov;
  }

  // V staging: 1024 jobs of 8 channels, transposed + swizzled + zero-padded
  for (int j = tid; j < 1024; j += 256) {
    int pp = j & 63, d8 = (j >> 6) & 3, hh = j >> 8;
    bf16 hv[8];
    if (pp < 49) {
      int r7 = (pp * 9363) >> 16, rm = pp - r7 * 7;
      const bf16* src = p.vb + gbase +
          ((size_t)((rh * 7 + r7) * f) * 56 + (rw * 7 + rm) * f) * 1152 + hh * 32 + d8 * 8;
      if (f == 1) {
        short8 v = *(const short8*)src;
#pragma unroll
        for (int e = 0; e < 8; ++e) { unsigned short bb = (unsigned short)v[e]; hv[e] = *(bf16*)&bb; }
      } else {
        float sum[8] = {}, mx[8];
#pragma unroll
        for (int e = 0; e < 8; ++e) mx[e] = -3.4e38f;
        for (int dy = 0; dy < f; ++dy)
          for (int dx = 0; dx < f; ++dx) {
            short8 v = *(const short8*)(src + ((size_t)dy * 56 + dx) * 1152);
#pragma unroll
            for (int e = 0; e < 8; ++e) {
              float fv = bf2f(v[e]); sum[e] += fv; mx[e] = fmaxf(mx[e], fv);
            }
          }
#pragma unroll
        for (int e = 0; e < 8; ++e) hv[e] = __float2bfloat16(sum[e] * pinv + mx[e]);
      }
    } else {
#pragma unroll
      for (int e = 0; e < 8; ++e) hv[e] = __float2bfloat16(0.f);
    }
#pragma unroll
    for (int e = 0; e < 8; ++e) {
      int d = d8 * 8 + e;
      Vt[hh * 2048 + d * 64 + ((pp >> 3) ^ (d & 7)) * 8 + (pp & 7)] = hv[e];
    }
  }

  // Q fragments (A-layout: row=lane&15, k=lk*8..+8), pooled if f>1
  short8 qa[4];
#pragma unroll
  for (int it = 0; it < 4; ++it) {
    int pq = it * 16 + lr; pq = min(pq, 48);
    int r7 = (pq * 9363) >> 16, rm = pq - r7 * 7;
    const bf16* src = p.qb + gbase +
        ((size_t)((rh * 7 + r7) * f) * 56 + (rw * 7 + rm) * f) * 1152 + h * 32 + lk * 8;
    if (f == 1) {
      qa[it] = *(const short8*)src;
    } else {
      float sum[8] = {}, mx[8];
#pragma unroll
      for (int e = 0; e < 8; ++e) mx[e] = -3.4e38f;
      for (int dy = 0; dy < f; ++dy)
        for (int dx = 0; dx < f; ++dx) {
          short8 v = *(const short8*)(src + ((size_t)dy * 56 + dx) * 1152);
#pragma unroll
          for (int e = 0; e < 8; ++e) {
            float fv = bf2f(v[e]); sum[e] += fv; mx[e] = fmaxf(mx[e], fv);
          }
        }
      union { short8 v; bf16 hh2[8]; } u;
#pragma unroll
      for (int e = 0; e < 8; ++e) u.hh2[e] = __float2bfloat16(sum[e] * pinv + mx[e]);
      qa[it] = u.v;
    }
  }

  __syncthreads();

  // QK^T: 16 MFMAs (K=32, single k-step)
  f32x4 s[4][4];
  {
    short8 kf[4];
#pragma unroll
    for (int jt = 0; jt < 4; ++jt)
      kf[jt] = *(const short8*)(KP + h * 4096 + (jt * 16 + lr) * 40 + lk * 8);
    const f32x4 z = {0.f, 0.f, 0.f, 0.f};
    __builtin_amdgcn_s_setprio(1);
#pragma unroll
    for (int it = 0; it < 4; ++it)
#pragma unroll
      for (int jt = 0; jt < 4; ++jt)
        s[it][jt] = __builtin_amdgcn_mfma_f32_16x16x32_bf16(qa[it], kf[jt], z, 0, 0, 0);
    __builtin_amdgcn_s_setprio(0);
  }

  // scale + bias + pad-mask + softmax (rows = lane&15 butterfly groups)
  const float scale = 0.17677669529663687f;
  const bool colpad = (lr != 0);               // jt==3: pp = 48+lr >= 49
  int pp7[4], ppm[4];
#pragma unroll
  for (int jt = 0; jt < 4; ++jt) {
    int pp = min(jt * 16 + lr, 48);
    pp7[jt] = (pp * 9363) >> 16; ppm[jt] = pp - pp7[jt] * 7;
  }
  float sm[4][4];
#pragma unroll
  for (int it = 0; it < 4; ++it)
#pragma unroll
    for (int t = 0; t < 4; ++t) {
      int pq = min(it * 16 + lk * 4 + t, 48);
      int q7 = (pq * 9363) >> 16, qm = pq - q7 * 7;
#pragma unroll
      for (int jt = 0; jt < 4; ++jt) {
        float bv = bias_s[(q7 - pp7[jt] + 6) * 13 + (qm - ppm[jt] + 6)];
        float v = fmaf(s[it][jt][t], scale, bv);
        if (jt == 3 && colpad) v = -1e30f;
        s[it][jt][t] = v;
      }
      float m = fmaxf(fmaxf(s[it][0][t], s[it][1][t]), fmaxf(s[it][2][t], s[it][3][t]));
      m = fmaxf(m, __shfl_xor(m, 1));
      m = fmaxf(m, __shfl_xor(m, 2));
      m = fmaxf(m, __shfl_xor(m, 4));
      m = fmaxf(m, __shfl_xor(m, 8));
      float ssum = 0.f;
#pragma unroll
      for (int jt = 0; jt < 4; ++jt) {
        float e = __expf(s[it][jt][t] - m);
        s[it][jt][t] = e; ssum += e;
      }
      ssum += __shfl_xor(ssum, 1);
      ssum += __shfl_xor(ssum, 2);
      ssum += __shfl_xor(ssum, 4);
      ssum += __shfl_xor(ssum, 8);
      sm[it][t] = 1.0f / ssum;
    }

  // P (unnormalized, <=1) -> same per-head LDS block (K is dead), XOR-swizzled
#pragma unroll
  for (int it = 0; it < 4; ++it)
#pragma unroll
    for (int t = 0; t < 4; ++t) {
      int prow = it * 16 + lk * 4 + t;
#pragma unroll
      for (int jt = 0; jt < 4; ++jt) {
        int slot = (jt * 2 + (lr >> 3)) ^ (prow & 7);
        KP[h * 4096 + prow * 64 + slot * 8 + (lr & 7)] = __float2bfloat16(s[it][jt][t]);
      }
    }
  __syncthreads();

  // PV: 16 MFMAs over 2 k-steps (pp 0..31, 32..63)
  f32x4 o[4][2] = {};
#pragma unroll
  for (int ks = 0; ks < 2; ++ks) {
    short8 pf[4], vf[2];
#pragma unroll
    for (int it = 0; it < 4; ++it) {
      int prow = it * 16 + lr;
      pf[it] = *(const short8*)(KP + h * 4096 + prow * 64 + ((ks * 4 + lk) ^ (prow & 7)) * 8);
    }
#pragma unroll
    for (int jd = 0; jd < 2; ++jd) {
      int d = jd * 16 + lr;
      vf[jd] = *(const short8*)(Vt + h * 2048 + d * 64 + ((ks * 4 + lk) ^ (d & 7)) * 8);
    }
    __builtin_amdgcn_s_setprio(1);
#pragma unroll
    for (int it = 0; it < 4; ++it)
#pragma unroll
      for (int jd = 0; jd < 2; ++jd)
        o[it][jd] = __builtin_amdgcn_mfma_f32_16x16x32_bf16(pf[it], vf[jd], o[it][jd], 0, 0, 0);
    __builtin_amdgcn_s_setprio(0);
  }

  // scrambled output scatter (matches reference reshape semantics)
  const int c0 = (r & 3) * 32;
#pragma unroll
  for (int it = 0; it < 4; ++it)
#pragma unroll
    for (int t = 0; t < 4; ++t) {
      int prow = it * 16 + lk * 4 + t;
      if (prow < 49) {
        int m_out = (h * (p.R >> 2) + (r >> 2)) * 49 + prow;
        bf16* op = p.out + ((size_t)b * p.npos + m_out) * p.out_cstride + p.out_coffset + c0;
#pragma unroll
        for (int jd = 0; jd < 2; ++jd)
          op[jd * 16 + lr] = __float2bfloat16(o[it][jd][t] * sm[it][t]);
      }
    }
}

// ---------------- Fused bilinear upsample for both scales ----------------
__device__ __forceinline__ float2 bilerp2(const bf16* __restrict__ base, int dim, int h, int w, int cp)
{
  float r = (float)dim / 56.f;
  float uy = (h + 0.5f) * r - 0.5f;
  float ux = (w + 0.5f) * r - 0.5f;
  float fy0 = floorf(uy), fx0 = floorf(ux);
  int y0 = (int)fy0, x0 = (int)fx0;
  float fy = uy - fy0, fx = ux - fx0;
  int y0c = max(y0, 0), y1c = min(y0 + 1, dim - 1);
  int x0c = max(x0, 0), x1c = min(x0 + 1, dim - 1);
  bf16x2 v00 = *(const bf16x2*)(base + ((size_t)y0c * dim + x0c) * 128 + cp * 2);
  bf16x2 v01 = *(const bf16x2*)(base + ((size_t)y0c * dim + x1c) * 128 + cp * 2);
  bf16x2 v10 = *(const bf16x2*)(base + ((size_t)y1c * dim + x0c) * 128 + cp * 2);
  bf16x2 v11 = *(const bf16x2*)(base + ((size_t)y1c * dim + x1c) * 128 + cp * 2);
  float w00 = (1.f - fy) * (1.f - fx), w01 = (1.f - fy) * fx;
  float w10 = fy * (1.f - fx),        w11 = fy * fx;
  float2 o;
  o.x = w00 * __bfloat162float(v00.x) + w01 * __bfloat162float(v01.x) +
        w10 * __bfloat162float(v10.x) + w11 * __bfloat162float(v11.x);
  o.y = w00 * __bfloat162float(v00.y) + w01 * __bfloat162float(v01.y) +
        w10 * __bfloat162float(v10.y) + w11 * __bfloat162float(v11.y);
  return o;
}

__global__ __launch_bounds__(256) void upsample_both_kernel(const bf16* __restrict__ yb1,
                                                            const bf16* __restrict__ yb2,
                                                            bf16* __restrict__ fused)
{
  int t = blockIdx.x * 256 + threadIdx.x;
  int cp = t & 63;
  int pos = t >> 6;
  int n = pos % 3136, b = pos / 3136;
  int h = n / 56, w = n % 56;
  float2 s1 = bilerp2(yb1 + (size_t)b * 784 * 128, 28, h, w, cp);
  float2 s2 = bilerp2(yb2 + (size_t)b * 196 * 128, 14, h, w, cp);
  bf16* op = fused + (size_t)pos * 384;
  bf16x2 o1; o1.x = __float2bfloat16(s1.x); o1.y = __float2bfloat16(s1.y);
  bf16x2 o2; o2.x = __float2bfloat16(s2.x); o2.y = __float2bfloat16(s2.y);
  *(bf16x2*)(op + 128 + cp * 2) = o1;
  *(bf16x2*)(op + 256 + cp * 2) = o2;
}

extern "C" void kernel_launch(void* const* d_in, const int* in_sizes, int n_in,
                              void* d_out, int out_size, void* d_ws, size_t ws_size,
                              hipStream_t stream)
{
  const float* x      = (const float*)d_in[0];
  const float* w_qkv  = (const float*)d_in[1];
  const float* w_proj = (const float*)d_in[2];
  const float* b_proj = (const float*)d_in[3];
  const float* btable = (const float*)d_in[4];

  bf16* temp  = (bf16*)d_ws;                          // 50176 x 1152
  bf16* fused = temp  + (size_t)50176 * 1152 + (size_t)3 * 16 * 980 * 128; // keep layout stable
  bf16* ybuf1 = fused + (size_t)50176 * 384;          // 16 x 784 x 128
  bf16* ybuf2 = ybuf1 + (size_t)16 * 784 * 128;       // 16 x 196 x 128
  bf16* wqkvT = ybuf2 + (size_t)16 * 196 * 128;       // 1152 x 384
  bf16* wprojT= wqkvT + (size_t)1152 * 384;           // 384 x 384
  bf16* xb    = fused;   // x in bf16, dead before attention writes fused

  // 0) prep: cvt + transposes in one launch
  prep_kernel<<<9408 + 2304, 256, 0, stream>>>(x, w_qkv, w_proj, xb, wqkvT, wprojT);

  // 1) QKV projection: temp = xb @ wqkvT^T  (196 x 9 = 1764 blocks, 512 thr)
  gemm_mfma<bf16, false><<<1764, 512, 0, stream>>>(
      xb, wqkvT, nullptr, temp, 50176, 1152, 384, 9);

  // 2) MFMA window attention with fused pooling; heavy f=4 blocks first
  AttnP P2{temp + 256, temp + 640, temp + 1024, ybuf2,
           4, 2, 4, 196, 128, 0, 0};
  AttnP P1{temp + 128, temp + 512, temp + 896, ybuf1,
           16, 4, 2, 784, 128, 0, 64};
  AttnP P0{temp, temp + 384, temp + 768, fused,
           64, 8, 1, 3136, 384, 0, 320};
  attn_mfma<<<1344, 256, 0, stream>>>(btable, P0, P1, P2);

  // 3) fused bilinear upsample into fused channels [128,256) and [256,384)
  upsample_both_kernel<<<16 * 3136 * 64 / 256, 256, 0, stream>>>(ybuf1, ybuf2, fused);

  // 4) output projection: out = fused @ wprojT^T + b_proj (196 x 3 = 588 blocks)
  gemm_mfma<float, true><<<588, 512, 0, stream>>>(
      fused, wprojT, b_proj, (float*)d_out, 50176, 384, 384, 3);
}

// Round 12
// 171.420 us; speedup vs baseline: 1.2348x; 1.1955x over previous
//
#include <hip/hip_runtime.h>
#include <hip/hip_bf16.h>

typedef __hip_bfloat16 bf16;
typedef __hip_bfloat162 bf16x2;
typedef __attribute__((ext_vector_type(8))) short short8;
typedef __attribute__((ext_vector_type(4))) float f32x4;

__device__ __forceinline__ float bf2f(short v) {
  return __uint_as_float(((unsigned)(unsigned short)v) << 16);
}
__device__ __forceinline__ bf16 rawbf(short v) {
  unsigned short b = (unsigned short)v; return *(bf16*)&b;
}
__device__ __forceinline__ void storeOut(float* p, float v) { *p = v; }
__device__ __forceinline__ void storeOut(bf16* p, float v) { *p = __float2bfloat16(v); }

#define GLOAD_LDS16(g, l)                                              \
  __builtin_amdgcn_global_load_lds(                                    \
      (const __attribute__((address_space(1))) void*)(g),              \
      (__attribute__((address_space(3))) void*)(l), 16, 0, 0)

// ---------------- prep: fp32->bf16 convert of x + both weight transposes ----------------
__global__ __launch_bounds__(256) void prep_kernel(const float* __restrict__ x,
                                                   const float* __restrict__ w_qkv,
                                                   const float* __restrict__ w_proj,
                                                   bf16* __restrict__ xb,
                                                   bf16* __restrict__ wqkvT,
                                                   bf16* __restrict__ wprojT)
{
  int bid = blockIdx.x;
  if (bid < 9408) {                       // cvt: 50176*384 elems, 2048/block
    int i = bid * 256 + threadIdx.x;
    const float4* p = (const float4*)x + (size_t)i * 2;
    float4 a = p[0], b = p[1];
    union { short8 v; bf16 h[8]; } u;
    u.h[0] = __float2bfloat16(a.x); u.h[1] = __float2bfloat16(a.y);
    u.h[2] = __float2bfloat16(a.z); u.h[3] = __float2bfloat16(a.w);
    u.h[4] = __float2bfloat16(b.x); u.h[5] = __float2bfloat16(b.y);
    u.h[6] = __float2bfloat16(b.z); u.h[7] = __float2bfloat16(b.w);
    *((short8*)xb + i) = u.v;
  } else {                                // transposes: 1152*384 + 384*384 elems
    int idx = (bid - 9408) * 256 + threadIdx.x;
    if (idx < 1152 * 384) {
      int n = idx / 384, k = idx - n * 384;
      wqkvT[idx] = __float2bfloat16(w_qkv[(size_t)k * 1152 + n]);
    } else {
      idx -= 1152 * 384;
      int n = idx / 384, k = idx - n * 384;
      wprojT[idx] = __float2bfloat16(w_proj[(size_t)k * 384 + n]);
    }
  }
}

// ---------------- MFMA GEMM: 256x128 tile, 8 waves, BK=64, single-buffer ----------------
// Round-9 verified config (65 us GEMM1; 2-phase structural ceiling per guide m233).
template<typename TC, bool BIAS>
__global__ __launch_bounds__(512) void gemm_mfma(const bf16* __restrict__ A,
                                                 const bf16* __restrict__ Bt,
                                                 const float* __restrict__ bias,
                                                 TC* __restrict__ C,
                                                 int M, int N, int K, int nbx)
{
  __shared__ __align__(16) bf16 As[256 * 64];   // 32 KB
  __shared__ __align__(16) bf16 Bs[128 * 64];   // 16 KB
  const int tid = threadIdx.x;
  const int wave = tid >> 6, lane = tid & 63;
  const int nwg = gridDim.x;
  const int qc = nwg >> 3, rr = nwg & 7;
  const int xcd = blockIdx.x & 7, jj = blockIdx.x >> 3;
  const int wg = (xcd < rr ? xcd * (qc + 1) : rr * (qc + 1) + (xcd - rr) * qc) + jj;
  const int by = wg / nbx, bx = wg - by * nbx;
  const int bm = by * 256, bn = bx * 128;
  const int wr = wave >> 1, wc = wave & 1;      // 4 x 2 wave grid

  f32x4 acc[4][4] = {};

  const bf16* aP[4];
  const bf16* bP[2];
#pragma unroll
  for (int e = 0; e < 4; ++e) {
    int flat = e * 8192 + tid * 16;
    int r = flat >> 7;
    int q = ((flat >> 4) & 7) ^ (r & 7);
    aP[e] = A + (size_t)(bm + r) * K + q * 8;
  }
#pragma unroll
  for (int e = 0; e < 2; ++e) {
    int flat = e * 8192 + tid * 16;
    int r = flat >> 7;
    int q = ((flat >> 4) & 7) ^ (r & 7);
    bP[e] = Bt + (size_t)(bn + r) * K + q * 8;
  }
  char* AsW = (char*)As + wave * 1024;
  char* BsW = (char*)Bs + wave * 1024;

  const int lr = lane & 15, lk = lane >> 4;
  const int rbA = (wr * 64 + lr) * 64;
  const int rbB = (wc * 64 + lr) * 64;
  const int q0 = ((lk    ) ^ (lr & 7)) * 8;
  const int q1 = ((4 + lk) ^ (lr & 7)) * 8;

  for (int k0 = 0; k0 < K; k0 += 64) {
#pragma unroll
    for (int e = 0; e < 4; ++e) GLOAD_LDS16(aP[e] + k0, AsW + e * 8192);
#pragma unroll
    for (int e = 0; e < 2; ++e) GLOAD_LDS16(bP[e] + k0, BsW + e * 8192);
    __syncthreads();
    short8 af0[4], af1[4], bf0[4], bf1[4];
#pragma unroll
    for (int i = 0; i < 4; ++i) {
      af0[i] = *(const short8*)(As + rbA + i * 1024 + q0);
      af1[i] = *(const short8*)(As + rbA + i * 1024 + q1);
    }
#pragma unroll
    for (int j = 0; j < 4; ++j) {
      bf0[j] = *(const short8*)(Bs + rbB + j * 1024 + q0);
      bf1[j] = *(const short8*)(Bs + rbB + j * 1024 + q1);
    }
#pragma unroll
    for (int i = 0; i < 4; ++i)
#pragma unroll
      for (int j = 0; j < 4; ++j) {
        acc[i][j] = __builtin_amdgcn_mfma_f32_16x16x32_bf16(af0[i], bf0[j], acc[i][j], 0, 0, 0);
        acc[i][j] = __builtin_amdgcn_mfma_f32_16x16x32_bf16(af1[i], bf1[j], acc[i][j], 0, 0, 0);
      }
    __syncthreads();
  }

  const int crow = bm + wr * 64 + lk * 4;
  const int ccol = bn + wc * 64 + lr;
#pragma unroll
  for (int j = 0; j < 4; ++j) {
    int col = ccol + j * 16;
    float bv = BIAS ? bias[col] : 0.f;
#pragma unroll
    for (int i = 0; i < 4; ++i)
#pragma unroll
      for (int t = 0; t < 4; ++t) {
        int row = crow + i * 16 + t;
        storeOut(&C[(size_t)row * N + col], acc[i][j][t] + bv);
      }
  }
}

// ---------------- MFMA window attention + fused pooling (template-F body) ----------------
// Block = one window; 4 waves = 4 heads. P=49 padded to 64.
// F is compile-time (1/2/4): pooling loops fully unroll -> batched loads.
// Coalesced staging: 16 consecutive threads read one position's 256B channel span.
struct AttnP {
  const bf16 *qb, *kb, *vb;
  bf16* out;
  int R, Rw, f, npos, out_cstride, out_coffset, blk0;
};

template<int F>
__device__ __forceinline__ void attn_body(const float* __restrict__ btable,
                                          const AttnP& p, int blk,
                                          bf16* KP, bf16* Vt, float* bias_s)
{
  const int b = blk / p.R, r = blk % p.R;
  const int rh = r / p.Rw, rw = r % p.Rw;
  const int tid = threadIdx.x;
  const int h = tid >> 6, lane = tid & 63;
  const int lr = lane & 15, lk = lane >> 4;
  const int hb = r & 3;
  const float pinv = 1.0f / (float)(F * F);

  if (tid < 169) bias_s[tid] = btable[tid * 4 + hb];

  const size_t gbase = (size_t)b * 3136 * 1152;

  // K staging: 784 jobs, coalesced mapping j = row*16 + hh*4 + slot
#pragma unroll
  for (int c0 = 0; c0 < 4; ++c0) {
    int j = c0 * 256 + tid;
    if (j < 784) {
      int row = j >> 4, r4 = j & 15;
      int hh = r4 >> 2, slot = r4 & 3;
      int r7 = (row * 9363) >> 16, rm = row - r7 * 7;
      const bf16* src = p.kb + gbase +
          ((size_t)((rh * 7 + r7) * F) * 56 + (rw * 7 + rm) * F) * 1152 + hh * 32 + slot * 8;
      short8 ov;
      if (F == 1) {
        ov = *(const short8*)src;
      } else {
        float sum[8] = {}, mx[8];
#pragma unroll
        for (int e = 0; e < 8; ++e) mx[e] = -3.4e38f;
#pragma unroll
        for (int dy = 0; dy < F; ++dy)
#pragma unroll
          for (int dx = 0; dx < F; ++dx) {
            short8 v = *(const short8*)(src + ((size_t)dy * 56 + dx) * 1152);
#pragma unroll
            for (int e = 0; e < 8; ++e) {
              float fv = bf2f(v[e]); sum[e] += fv; mx[e] = fmaxf(mx[e], fv);
            }
          }
        union { short8 v; bf16 hb8[8]; } u;
#pragma unroll
        for (int e = 0; e < 8; ++e) u.hb8[e] = __float2bfloat16(sum[e] * pinv + mx[e]);
        ov = u.v;
      }
      *(short8*)(KP + hh * 4096 + row * 40 + slot * 8) = ov;
    }
  }

  // V staging: 1024 jobs, coalesced mapping j = pp*16 + hh*4 + d8
#pragma unroll
  for (int c0 = 0; c0 < 4; ++c0) {
    int j = c0 * 256 + tid;
    int pp = j >> 4, r4 = j & 15;
    int hh = r4 >> 2, d8 = r4 & 3;
    bf16 hv[8];
    if (pp < 49) {
      int r7 = (pp * 9363) >> 16, rm = pp - r7 * 7;
      const bf16* src = p.vb + gbase +
          ((size_t)((rh * 7 + r7) * F) * 56 + (rw * 7 + rm) * F) * 1152 + hh * 32 + d8 * 8;
      if (F == 1) {
        short8 v = *(const short8*)src;
#pragma unroll
        for (int e = 0; e < 8; ++e) hv[e] = rawbf(v[e]);
      } else {
        float sum[8] = {}, mx[8];
#pragma unroll
        for (int e = 0; e < 8; ++e) mx[e] = -3.4e38f;
#pragma unroll
        for (int dy = 0; dy < F; ++dy)
#pragma unroll
          for (int dx = 0; dx < F; ++dx) {
            short8 v = *(const short8*)(src + ((size_t)dy * 56 + dx) * 1152);
#pragma unroll
            for (int e = 0; e < 8; ++e) {
              float fv = bf2f(v[e]); sum[e] += fv; mx[e] = fmaxf(mx[e], fv);
            }
          }
#pragma unroll
        for (int e = 0; e < 8; ++e) hv[e] = __float2bfloat16(sum[e] * pinv + mx[e]);
      }
    } else {
#pragma unroll
      for (int e = 0; e < 8; ++e) hv[e] = __float2bfloat16(0.f);
    }
#pragma unroll
    for (int e = 0; e < 8; ++e) {
      int d = d8 * 8 + e;
      Vt[hh * 2048 + d * 64 + ((pp >> 3) ^ (d & 7)) * 8 + (pp & 7)] = hv[e];
    }
  }

  // Q fragments (A-layout: row=lane&15, k=lk*8..+8), pooled if F>1
  short8 qa[4];
#pragma unroll
  for (int it = 0; it < 4; ++it) {
    int pq = it * 16 + lr; pq = min(pq, 48);
    int r7 = (pq * 9363) >> 16, rm = pq - r7 * 7;
    const bf16* src = p.qb + gbase +
        ((size_t)((rh * 7 + r7) * F) * 56 + (rw * 7 + rm) * F) * 1152 + h * 32 + lk * 8;
    if (F == 1) {
      qa[it] = *(const short8*)src;
    } else {
      float sum[8] = {}, mx[8];
#pragma unroll
      for (int e = 0; e < 8; ++e) mx[e] = -3.4e38f;
#pragma unroll
      for (int dy = 0; dy < F; ++dy)
#pragma unroll
        for (int dx = 0; dx < F; ++dx) {
          short8 v = *(const short8*)(src + ((size_t)dy * 56 + dx) * 1152);
#pragma unroll
          for (int e = 0; e < 8; ++e) {
            float fv = bf2f(v[e]); sum[e] += fv; mx[e] = fmaxf(mx[e], fv);
          }
        }
      union { short8 v; bf16 hb8[8]; } u;
#pragma unroll
      for (int e = 0; e < 8; ++e) u.hb8[e] = __float2bfloat16(sum[e] * pinv + mx[e]);
      qa[it] = u.v;
    }
  }

  __syncthreads();

  // QK^T: 16 MFMAs (K=32, single k-step)
  f32x4 s[4][4];
  {
    short8 kf[4];
#pragma unroll
    for (int jt = 0; jt < 4; ++jt)
      kf[jt] = *(const short8*)(KP + h * 4096 + (jt * 16 + lr) * 40 + lk * 8);
    const f32x4 z = {0.f, 0.f, 0.f, 0.f};
    __builtin_amdgcn_s_setprio(1);
#pragma unroll
    for (int it = 0; it < 4; ++it)
#pragma unroll
      for (int jt = 0; jt < 4; ++jt)
        s[it][jt] = __builtin_amdgcn_mfma_f32_16x16x32_bf16(qa[it], kf[jt], z, 0, 0, 0);
    __builtin_amdgcn_s_setprio(0);
  }

  // scale + bias + pad-mask + softmax (rows = lane&15 butterfly groups)
  const float scale = 0.17677669529663687f;
  const bool colpad = (lr != 0);               // jt==3: pp = 48+lr >= 49
  int pp7[4], ppm[4];
#pragma unroll
  for (int jt = 0; jt < 4; ++jt) {
    int pp = min(jt * 16 + lr, 48);
    pp7[jt] = (pp * 9363) >> 16; ppm[jt] = pp - pp7[jt] * 7;
  }
  float sm[4][4];
#pragma unroll
  for (int it = 0; it < 4; ++it)
#pragma unroll
    for (int t = 0; t < 4; ++t) {
      int pq = min(it * 16 + lk * 4 + t, 48);
      int q7 = (pq * 9363) >> 16, qm = pq - q7 * 7;
#pragma unroll
      for (int jt = 0; jt < 4; ++jt) {
        float bv = bias_s[(q7 - pp7[jt] + 6) * 13 + (qm - ppm[jt] + 6)];
        float v = fmaf(s[it][jt][t], scale, bv);
        if (jt == 3 && colpad) v = -1e30f;
        s[it][jt][t] = v;
      }
      float m = fmaxf(fmaxf(s[it][0][t], s[it][1][t]), fmaxf(s[it][2][t], s[it][3][t]));
      m = fmaxf(m, __shfl_xor(m, 1));
      m = fmaxf(m, __shfl_xor(m, 2));
      m = fmaxf(m, __shfl_xor(m, 4));
      m = fmaxf(m, __shfl_xor(m, 8));
      float ssum = 0.f;
#pragma unroll
      for (int jt = 0; jt < 4; ++jt) {
        float e = __expf(s[it][jt][t] - m);
        s[it][jt][t] = e; ssum += e;
      }
      ssum += __shfl_xor(ssum, 1);
      ssum += __shfl_xor(ssum, 2);
      ssum += __shfl_xor(ssum, 4);
      ssum += __shfl_xor(ssum, 8);
      sm[it][t] = 1.0f / ssum;
    }

  // P (unnormalized, <=1) -> same per-head LDS block (K is dead), XOR-swizzled
#pragma unroll
  for (int it = 0; it < 4; ++it)
#pragma unroll
    for (int t = 0; t < 4; ++t) {
      int prow = it * 16 + lk * 4 + t;
#pragma unroll
      for (int jt = 0; jt < 4; ++jt) {
        int slot = (jt * 2 + (lr >> 3)) ^ (prow & 7);
        KP[h * 4096 + prow * 64 + slot * 8 + (lr & 7)] = __float2bfloat16(s[it][jt][t]);
      }
    }
  __syncthreads();

  // PV: 16 MFMAs over 2 k-steps (pp 0..31, 32..63)
  f32x4 o[4][2] = {};
#pragma unroll
  for (int ks = 0; ks < 2; ++ks) {
    short8 pf[4], vf[2];
#pragma unroll
    for (int it = 0; it < 4; ++it) {
      int prow = it * 16 + lr;
      pf[it] = *(const short8*)(KP + h * 4096 + prow * 64 + ((ks * 4 + lk) ^ (prow & 7)) * 8);
    }
#pragma unroll
    for (int jd = 0; jd < 2; ++jd) {
      int d = jd * 16 + lr;
      vf[jd] = *(const short8*)(Vt + h * 2048 + d * 64 + ((ks * 4 + lk) ^ (d & 7)) * 8);
    }
    __builtin_amdgcn_s_setprio(1);
#pragma unroll
    for (int it = 0; it < 4; ++it)
#pragma unroll
      for (int jd = 0; jd < 2; ++jd)
        o[it][jd] = __builtin_amdgcn_mfma_f32_16x16x32_bf16(pf[it], vf[jd], o[it][jd], 0, 0, 0);
    __builtin_amdgcn_s_setprio(0);
  }

  // scrambled output scatter (matches reference reshape semantics)
  const int c0 = (r & 3) * 32;
#pragma unroll
  for (int it = 0; it < 4; ++it)
#pragma unroll
    for (int t = 0; t < 4; ++t) {
      int prow = it * 16 + lk * 4 + t;
      if (prow < 49) {
        int m_out = (h * (p.R >> 2) + (r >> 2)) * 49 + prow;
        bf16* op = p.out + ((size_t)b * p.npos + m_out) * p.out_cstride + p.out_coffset + c0;
#pragma unroll
        for (int jd = 0; jd < 2; ++jd)
          op[jd * 16 + lr] = __float2bfloat16(o[it][jd][t] * sm[it][t]);
      }
    }
}

__global__ __launch_bounds__(256) void attn_mfma(const float* __restrict__ btable,
                                                 AttnP P0, AttnP P1, AttnP P2)
{
  __shared__ __align__(16) bf16 KP[4 * 4096];      // [h]: K rows [64][40] then P [64][64]
  __shared__ __align__(16) bf16 Vt[4 * 2048];      // [h][d][pp] swizzled, pp>=49 zeroed
  __shared__ float bias_s[169];

  const AttnP p = (blockIdx.x >= (unsigned)P0.blk0) ? P0
                : (blockIdx.x >= (unsigned)P1.blk0) ? P1 : P2;
  const int blk = blockIdx.x - p.blk0;
  if (p.f == 1)      attn_body<1>(btable, p, blk, KP, Vt, bias_s);
  else if (p.f == 2) attn_body<2>(btable, p, blk, KP, Vt, bias_s);
  else               attn_body<4>(btable, p, blk, KP, Vt, bias_s);
}

// ---------------- Fused bilinear upsample for both scales ----------------
__device__ __forceinline__ float2 bilerp2(const bf16* __restrict__ base, int dim, int h, int w, int cp)
{
  float r = (float)dim / 56.f;
  float uy = (h + 0.5f) * r - 0.5f;
  float ux = (w + 0.5f) * r - 0.5f;
  float fy0 = floorf(uy), fx0 = floorf(ux);
  int y0 = (int)fy0, x0 = (int)fx0;
  float fy = uy - fy0, fx = ux - fx0;
  int y0c = max(y0, 0), y1c = min(y0 + 1, dim - 1);
  int x0c = max(x0, 0), x1c = min(x0 + 1, dim - 1);
  bf16x2 v00 = *(const bf16x2*)(base + ((size_t)y0c * dim + x0c) * 128 + cp * 2);
  bf16x2 v01 = *(const bf16x2*)(base + ((size_t)y0c * dim + x1c) * 128 + cp * 2);
  bf16x2 v10 = *(const bf16x2*)(base + ((size_t)y1c * dim + x0c) * 128 + cp * 2);
  bf16x2 v11 = *(const bf16x2*)(base + ((size_t)y1c * dim + x1c) * 128 + cp * 2);
  float w00 = (1.f - fy) * (1.f - fx), w01 = (1.f - fy) * fx;
  float w10 = fy * (1.f - fx),        w11 = fy * fx;
  float2 o;
  o.x = w00 * __bfloat162float(v00.x) + w01 * __bfloat162float(v01.x) +
        w10 * __bfloat162float(v10.x) + w11 * __bfloat162float(v11.x);
  o.y = w00 * __bfloat162float(v00.y) + w01 * __bfloat162float(v01.y) +
        w10 * __bfloat162float(v10.y) + w11 * __bfloat162float(v11.y);
  return o;
}

__global__ __launch_bounds__(256) void upsample_both_kernel(const bf16* __restrict__ yb1,
                                                            const bf16* __restrict__ yb2,
                                                            bf16* __restrict__ fused)
{
  int t = blockIdx.x * 256 + threadIdx.x;
  int cp = t & 63;
  int pos = t >> 6;
  int n = pos % 3136, b = pos / 3136;
  int h = n / 56, w = n % 56;
  float2 s1 = bilerp2(yb1 + (size_t)b * 784 * 128, 28, h, w, cp);
  float2 s2 = bilerp2(yb2 + (size_t)b * 196 * 128, 14, h, w, cp);
  bf16* op = fused + (size_t)pos * 384;
  bf16x2 o1; o1.x = __float2bfloat16(s1.x); o1.y = __float2bfloat16(s1.y);
  bf16x2 o2; o2.x = __float2bfloat16(s2.x); o2.y = __float2bfloat16(s2.y);
  *(bf16x2*)(op + 128 + cp * 2) = o1;
  *(bf16x2*)(op + 256 + cp * 2) = o2;
}

extern "C" void kernel_launch(void* const* d_in, const int* in_sizes, int n_in,
                              void* d_out, int out_size, void* d_ws, size_t ws_size,
                              hipStream_t stream)
{
  const float* x      = (const float*)d_in[0];
  const float* w_qkv  = (const float*)d_in[1];
  const float* w_proj = (const float*)d_in[2];
  const float* b_proj = (const float*)d_in[3];
  const float* btable = (const float*)d_in[4];

  bf16* temp  = (bf16*)d_ws;                          // 50176 x 1152
  bf16* fused = temp  + (size_t)50176 * 1152 + (size_t)3 * 16 * 980 * 128;
  bf16* ybuf1 = fused + (size_t)50176 * 384;          // 16 x 784 x 128
  bf16* ybuf2 = ybuf1 + (size_t)16 * 784 * 128;       // 16 x 196 x 128
  bf16* wqkvT = ybuf2 + (size_t)16 * 196 * 128;       // 1152 x 384
  bf16* wprojT= wqkvT + (size_t)1152 * 384;           // 384 x 384
  bf16* xb    = fused;   // x in bf16, dead before attention writes fused

  // 0) prep: cvt + transposes in one launch
  prep_kernel<<<9408 + 2304, 256, 0, stream>>>(x, w_qkv, w_proj, xb, wqkvT, wprojT);

  // 1) QKV projection: temp = xb @ wqkvT^T  (196 x 9 = 1764 blocks, 512 thr)
  gemm_mfma<bf16, false><<<1764, 512, 0, stream>>>(
      xb, wqkvT, nullptr, temp, 50176, 1152, 384, 9);

  // 2) MFMA window attention with fused pooling; heavy f=4 blocks first
  AttnP P2{temp + 256, temp + 640, temp + 1024, ybuf2,
           4, 2, 4, 196, 128, 0, 0};
  AttnP P1{temp + 128, temp + 512, temp + 896, ybuf1,
           16, 4, 2, 784, 128, 0, 64};
  AttnP P0{temp, temp + 384, temp + 768, fused,
           64, 8, 1, 3136, 384, 0, 320};
  attn_mfma<<<1344, 256, 0, stream>>>(btable, P0, P1, P2);

  // 3) fused bilinear upsample into fused channels [128,256) and [256,384)
  upsample_both_kernel<<<16 * 3136 * 64 / 256, 256, 0, stream>>>(ybuf1, ybuf2, fused);

  // 4) output projection: out = fused @ wprojT^T + b_proj (196 x 3 = 588 blocks)
  gemm_mfma<float, true><<<588, 512, 0, stream>>>(
      fused, wprojT, b_proj, (float*)d_out, 50176, 384, 384, 3);
}